// Round 8
// baseline (571.527 us; speedup 1.0000x reference)
//
#include <hip/hip_runtime.h>
#include <hip/hip_bf16.h>

// C[m,n] = sum_{r,k} A[r][m][k] * B[r][n][k]
// Phase 1: convert A,B -> bf16 in d_ws (K contiguous: k' = r*1024+k).
// Phase 2: 256x256 GEMM, 16x16x32 MFMA, 8 waves (2Mx4N), T2 swizzle.
// r7->r8: r7 refuted the LDS-pipe theory (cutting reads 2816->2176cy was
//         neutral). Limiter = 8 barrier+waitcnt sync points/tile in lockstep
//         (~1500cy/tile). New schedule: ONE barrier per K-tile; intra-tile
//         is a barrier-free pipeline with counted lgkm between MFMA clusters.
//         Entry: vmcnt(0) [own stage rows, issued a full tile ago -> free]
//         + BAR [publishes cross-wave stages; proves all drained t-1 reads].

#define M_TOT 8192
#define N_TOT 4096
#define LK    1024
#define NR    8
#define K_TOT (NR * LK)    // 8192
#define NT    (K_TOT / 64) // 128 K-tiles

typedef float f32x4 __attribute__((ext_vector_type(4)));
typedef short s16x8 __attribute__((ext_vector_type(8)));
typedef const __attribute__((address_space(1))) unsigned int* gptr_t;
typedef __attribute__((address_space(3))) unsigned int* lptr_t;

__device__ inline short f2bf(float f) {
    __hip_bfloat16 h = __float2bfloat16(f);
    return *reinterpret_cast<short*>(&h);
}

// ---------------- convert pre-pass ----------------
__global__ __launch_bounds__(256)
void cvt_bf16(const float* __restrict__ in, short* __restrict__ out,
              int row_shift, int row_mask) {
    const int row = blockIdx.x * 2 + (threadIdx.x >> 7);
    const int c   = (threadIdx.x & 127) * 8;
    const int r   = row >> row_shift;
    const int m   = row & row_mask;
    const float* src = in + ((size_t)row << 10) + c;
    f32x4 v0 = *(const f32x4*)src;
    f32x4 v1 = *(const f32x4*)(src + 4);
    s16x8 o;
    #pragma unroll
    for (int j = 0; j < 4; ++j) { o[j] = f2bf(v0[j]); o[j + 4] = f2bf(v1[j]); }
    *(s16x8*)(out + ((size_t)m << 13) + ((size_t)r << 10) + c) = o;
}

// ---------------- GEMM helpers ----------------
// LDS: buf P at P*32768 shorts; A-tile [256][64] at +0, B-tile at +16384.
// Swizzle: LDS granule g of row r holds global granule g ^ (r&7).

__device__ __forceinline__ void stage_half(const short* srcBase, short* ldsOp,
                                           int half, int ktile, int wid) {
    #pragma unroll
    for (int q = 0; q < 2; ++q) {
        const short* src = srcBase + (size_t)(half * 128 + q * 8) * K_TOT + ktile * 64;
        short* dst = ldsOp + (half * 128 + wid * 16 + q * 8) * 64;  // wave-uniform
        __builtin_amdgcn_global_load_lds((gptr_t)src, (lptr_t)dst, 16, 0, 0);
    }
}

// A cluster C: frags at rows C*64 + wm*32 + {0,16} + r15; rotated slot C&1
template<int C>
__device__ __forceinline__ void read_a_pair(s16x8 (&afr)[2][2][2], const short* lAc,
                                            int wm, int r15, int kg) {
    #pragma unroll
    for (int fo = 0; fo < 2; ++fo)
        #pragma unroll
        for (int ks = 0; ks < 2; ++ks) {
            const int row = C * 64 + wm * 32 + fo * 16 + r15;
            const int off = row * 64 + ((((ks << 2) | kg) ^ (row & 7)) << 3);
            afr[C & 1][fo][ks] = *(const s16x8*)(lAc + off);
        }
}

__device__ __forceinline__ void read_b(s16x8 (&bfr)[4][2], const short* lBc,
                                       int wn, int r15, int kg) {
    #pragma unroll
    for (int n = 0; n < 4; ++n)
        #pragma unroll
        for (int ks = 0; ks < 2; ++ks) {
            const int row = wn * 64 + n * 16 + r15;
            const int off = row * 64 + ((((ks << 2) | kg) ^ (row & 7)) << 3);
            bfr[n][ks] = *(const s16x8*)(lBc + off);
        }
}

template<int Q>
__device__ __forceinline__ void mfma_quad(f32x4 (&acc)[8][4], s16x8 (&afr)[2][2][2],
                                          s16x8 (&bfr)[4][2]) {
    __builtin_amdgcn_s_setprio(1);
    #pragma unroll
    for (int fo = 0; fo < 2; ++fo)
        #pragma unroll
        for (int n = 0; n < 4; ++n)
            #pragma unroll
            for (int ks = 0; ks < 2; ++ks)
                acc[Q * 2 + fo][n] = __builtin_amdgcn_mfma_f32_16x16x32_bf16(
                    afr[Q & 1][fo][ks], bfr[n][ks], acc[Q * 2 + fo][n], 0, 0, 0);
    __builtin_amdgcn_s_setprio(0);
}

#define MEMCLOB asm volatile("" ::: "memory")
#define BAR     __builtin_amdgcn_s_barrier()
#define SCHED0  __builtin_amdgcn_sched_barrier(0)

__global__ __launch_bounds__(512, 1)
void gemm8(const short* __restrict__ A, const short* __restrict__ B,
           float* __restrict__ C) {
    extern __shared__ short smem[];

    const int tid  = threadIdx.x;
    const int lane = tid & 63;
    const int wid  = tid >> 6;
    const int wm   = wid >> 2;      // 0..1
    const int wn   = wid & 3;       // 0..3
    const int r15  = lane & 15;
    const int kg   = lane >> 4;     // 0..3
    const int l8   = lane >> 3;     // 0..7
    const int g16  = (lane & 7) ^ l8;  // pre-swizzled source granule

    const int bid = blockIdx.x;
    const int sw  = (bid & 7) * 64 + (bid >> 3);   // bijective (512 % 8 == 0)
    const int bm  = sw >> 4;   // 0..31
    const int bn  = sw & 15;   // 0..15

    const short* srcA = A + (size_t)(bm * 256 + wid * 16 + l8) * K_TOT + g16 * 8;
    const short* srcB = B + (size_t)(bn * 256 + wid * 16 + l8) * K_TOT + g16 * 8;

    // Prologue: stage tile0 only (8 instrs). Loop entry handles the rest.
    stage_half(srcB, smem + 16384, 0, 0, wid);
    stage_half(srcB, smem + 16384, 1, 0, wid);
    stage_half(srcA, smem,         0, 0, wid);
    stage_half(srcA, smem,         1, 0, wid);

    f32x4 acc[8][4];
    #pragma unroll
    for (int f = 0; f < 8; ++f)
        #pragma unroll
        for (int n = 0; n < 4; ++n)
            acc[f][n] = (f32x4){0.f, 0.f, 0.f, 0.f};

    s16x8 afr[2][2][2];
    s16x8 bfr[4][2];

    for (int t = 0; t < NT; ++t) {
        const int par = t & 1;
        const short* bufC = smem + (par << 15);        // tile t data
        short* bufN = smem + ((par ^ 1) << 15);        // tile t+1 dest

        // ---- tile entry: my stage rows of t landed (issued a full tile ago);
        //      BAR publishes all waves' rows AND proves all drained t-1 reads.
        asm volatile("s_waitcnt vmcnt(0)" ::: "memory");
        MEMCLOB; BAR;

        // issue this tile's leading reads (B all + c0 + c1 = 16 ds_reads)
        read_b(bfr, bufC + 16384, wn, r15, kg);
        read_a_pair<0>(afr, bufC, wm, r15, kg);
        read_a_pair<1>(afr, bufC, wm, r15, kg);

        // stage tile t+1 (async; counted by vmcnt only, never drained mid-tile)
        if (t + 1 < NT) {
            stage_half(srcB, bufN + 16384, 0, t + 1, wid);
            stage_half(srcB, bufN + 16384, 1, t + 1, wid);
            stage_half(srcA, bufN,         0, t + 1, wid);
            stage_half(srcA, bufN,         1, t + 1, wid);
        }

        // ---- barrier-free intra-tile pipeline, counted lgkm per cluster
        asm volatile("s_waitcnt lgkmcnt(4)" ::: "memory"); SCHED0;  // B+c0 done
        mfma_quad<0>(acc, afr, bfr);
        read_a_pair<2>(afr, bufC, wm, r15, kg);
        asm volatile("s_waitcnt lgkmcnt(4)" ::: "memory"); SCHED0;  // c1 done
        mfma_quad<1>(acc, afr, bfr);
        read_a_pair<3>(afr, bufC, wm, r15, kg);
        asm volatile("s_waitcnt lgkmcnt(4)" ::: "memory"); SCHED0;  // c2 done
        mfma_quad<2>(acc, afr, bfr);
        asm volatile("s_waitcnt lgkmcnt(0)" ::: "memory"); SCHED0;  // c3 done
        mfma_quad<3>(acc, afr, bfr);
        MEMCLOB;   // keep reads/MFMA on this side of next entry BAR
    }

    // Epilogue: 16x16 C/D layout col=lane&15, row=(lane>>4)*4+jj [m89-verified]
    float* Cp = C + (size_t)(bm * 256 + wm * 32 + kg * 4) * N_TOT
                  + bn * 256 + wn * 64 + r15;
    #pragma unroll
    for (int f = 0; f < 8; ++f)
        #pragma unroll
        for (int n = 0; n < 4; ++n)
            #pragma unroll
            for (int jj = 0; jj < 4; ++jj) {
                const int roff = (f >> 1) * 64 + (f & 1) * 16 + jj;
                Cp[(size_t)roff * N_TOT + n * 16] = acc[f][n][jj];
            }
}

// ---------------- fallback (only if ws too small) ----------------
#define PAD_ROW 40
__global__ __launch_bounds__(256, 2)
void gemm_rs_fused(const float* __restrict__ A, const float* __restrict__ B,
                   float* __restrict__ C) {
    __shared__ short lA[128 * PAD_ROW];
    __shared__ short lB[128 * PAD_ROW];
    const int bid = blockIdx.x;
    const int sw  = (bid & 7) * (int)(gridDim.x >> 3) + (bid >> 3);
    const int bm = sw >> 5, bn = sw & 31;
    const int tid = threadIdx.x, lane = tid & 63, wid = tid >> 6;
    const int wr = wid >> 1, wc = wid & 1, r15 = lane & 15, kg = lane >> 4;
    const int srow = tid >> 1, scg = tid & 1;
    const float* gA = A + ((size_t)(bm * 128 + srow) << 10) + scg * 16;
    const float* gB = B + ((size_t)(bn * 128 + srow) << 10) + scg * 16;
    short* wpA = lA + srow * PAD_ROW + scg * 16;
    short* wpB = lB + srow * PAD_ROW + scg * 16;
    const short* rpA = lA + (wr * 64 + r15) * PAD_ROW + kg * 8;
    const short* rpB = lB + (wc * 64 + r15) * PAD_ROW + kg * 8;
    f32x4 acc[4][4];
    #pragma unroll
    for (int i = 0; i < 4; ++i)
        #pragma unroll
        for (int j = 0; j < 4; ++j) acc[i][j] = (f32x4){0.f, 0.f, 0.f, 0.f};
    for (int t = 0; t < K_TOT / 32; ++t) {
        const int r = t >> 5, k0 = (t & 31) << 5;
        const float* pA = gA + (size_t)r * (M_TOT * LK) + k0;
        const float* pB = gB + (size_t)r * (N_TOT * LK) + k0;
        f32x4 va[4], vb[4];
        #pragma unroll
        for (int q = 0; q < 4; ++q) va[q] = *(const f32x4*)(pA + q * 4);
        #pragma unroll
        for (int q = 0; q < 4; ++q) vb[q] = *(const f32x4*)(pB + q * 4);
        __syncthreads();
        s16x8 oa0, oa1, ob0, ob1;
        #pragma unroll
        for (int q = 0; q < 2; ++q)
            #pragma unroll
            for (int i = 0; i < 4; ++i) {
                oa0[q * 4 + i] = f2bf(va[q][i]);
                oa1[q * 4 + i] = f2bf(va[q + 2][i]);
                ob0[q * 4 + i] = f2bf(vb[q][i]);
                ob1[q * 4 + i] = f2bf(vb[q + 2][i]);
            }
        *(s16x8*)(wpA) = oa0; *(s16x8*)(wpA + 8) = oa1;
        *(s16x8*)(wpB) = ob0; *(s16x8*)(wpB + 8) = ob1;
        __syncthreads();
        s16x8 af[4], bfr2[4];
        #pragma unroll
        for (int i = 0; i < 4; ++i) af[i]   = *(const s16x8*)(rpA + i * 16 * PAD_ROW);
        #pragma unroll
        for (int i = 0; i < 4; ++i) bfr2[i] = *(const s16x8*)(rpB + i * 16 * PAD_ROW);
        #pragma unroll
        for (int i = 0; i < 4; ++i)
            #pragma unroll
            for (int j = 0; j < 4; ++j)
                acc[i][j] = __builtin_amdgcn_mfma_f32_16x16x32_bf16(
                    af[i], bfr2[j], acc[i][j], 0, 0, 0);
    }
    float* Cp = C + (size_t)(bm * 128 + wr * 64 + kg * 4) * N_TOT
                  + bn * 128 + wc * 64 + r15;
    #pragma unroll
    for (int i = 0; i < 4; ++i)
        #pragma unroll
        for (int j = 0; j < 4; ++j)
            #pragma unroll
            for (int jj = 0; jj < 4; ++jj)
                Cp[(size_t)(i * 16 + jj) * N_TOT + j * 16] = acc[i][j][jj];
}

extern "C" void kernel_launch(void* const* d_in, const int* in_sizes, int n_in,
                              void* d_out, int out_size, void* d_ws, size_t ws_size,
                              hipStream_t stream) {
    const float* A = (const float*)d_in[0];   // [8, 8192, 1024]
    const float* B = (const float*)d_in[1];   // [8, 4096, 1024]
    float* C = (float*)d_out;                 // [8192, 4096]

    const size_t needA = (size_t)M_TOT * K_TOT * 2;
    const size_t needB = (size_t)N_TOT * K_TOT * 2;

    if (ws_size >= needA + needB) {
        short* Abf = (short*)d_ws;
        short* Bbf = (short*)((char*)d_ws + needA);
        cvt_bf16<<<dim3(NR * M_TOT / 2), dim3(256), 0, stream>>>(A, Abf, 13, 8191);
        cvt_bf16<<<dim3(NR * N_TOT / 2), dim3(256), 0, stream>>>(B, Bbf, 12, 4095);
        gemm8<<<dim3((M_TOT / 256) * (N_TOT / 256)), dim3(512), 131072, stream>>>(Abf, Bbf, C);
    } else {
        gemm_rs_fused<<<dim3((M_TOT / 128) * (N_TOT / 128)), dim3(256), 0, stream>>>(A, B, C);
    }
}

// Round 10
// 519.226 us; speedup vs baseline: 1.1007x; 1.1007x over previous
//
#include <hip/hip_runtime.h>
#include <hip/hip_bf16.h>

// C[m,n] = sum_{r,k} A[r][m][k] * B[r][n][k]
// Phase 1: merged convert A,B -> bf16 in d_ws (K contiguous: k' = r*1024+k).
// Phase 2: r6 schedule (best: 427us GEMM), addressing rewritten:
//          - ds_reads: 4 base VGPRs/parity + compile-time immediate offsets
//          - staging: 2 running global ptrs (+=64/tile) + const deltas
//          r9 fix: INTERLEAVE_STEP takes parity as explicit macro arg
//          (nested macro can't see TILE_BODY's parameter).

#define M_TOT 8192
#define N_TOT 4096
#define LK    1024
#define NR    8
#define K_TOT (NR * LK)    // 8192
#define NT    (K_TOT / 64) // 128 K-tiles

typedef float f32x4 __attribute__((ext_vector_type(4)));
typedef short s16x8 __attribute__((ext_vector_type(8)));
typedef const __attribute__((address_space(1))) unsigned int* gptr_t;
typedef __attribute__((address_space(3))) unsigned int* lptr_t;

__device__ inline short f2bf(float f) {
    __hip_bfloat16 h = __float2bfloat16(f);
    return *reinterpret_cast<short*>(&h);
}

// ---------------- merged convert pre-pass ----------------
// blocks [0, 32768): A rows (65536 rows of 1024, shift13/mask8191)
// blocks [32768, 49152): B rows (32768 rows, shift12/mask4095)
__global__ __launch_bounds__(256)
void cvt_all(const float* __restrict__ A, const float* __restrict__ B,
             short* __restrict__ Abf, short* __restrict__ Bbf) {
    int bid = blockIdx.x;
    const float* in;
    short* out;
    int row_shift, row_mask;
    if (bid < 32768) { in = A; out = Abf; row_shift = 13; row_mask = 8191; }
    else { bid -= 32768; in = B; out = Bbf; row_shift = 12; row_mask = 4095; }
    const int row = bid * 2 + (threadIdx.x >> 7);
    const int c   = (threadIdx.x & 127) * 8;
    const int r   = row >> row_shift;
    const int m   = row & row_mask;
    const float* src = in + ((size_t)row << 10) + c;
    f32x4 v0 = *(const f32x4*)src;
    f32x4 v1 = *(const f32x4*)(src + 4);
    s16x8 o;
    #pragma unroll
    for (int j = 0; j < 4; ++j) { o[j] = f2bf(v0[j]); o[j + 4] = f2bf(v1[j]); }
    *(s16x8*)(out + ((size_t)m << 13) + ((size_t)r << 10) + c) = o;
}

// ---------------- GEMM ----------------
// LDS: buf P at P*32768 shorts; A-tile [256][64] at +0, B-tile at +16384.
// Swizzle: LDS granule g of row r holds global granule g ^ (r&7).

// stage one half-tile (HALF) of tile t+D; g = per-lane src at tile t's k-offset;
// l = per-parity wave-uniform LDS dest base (includes wid*1024).
template<int HALF, int D>
__device__ __forceinline__ void stage(const short* g, short* l) {
    #pragma unroll
    for (int q = 0; q < 2; ++q) {
        const short* src = g + (size_t)(HALF * 128 + q * 8) * K_TOT + D * 64;
        short* dst = l + (HALF * 128 + q * 8) * 64;
        __builtin_amdgcn_global_load_lds((gptr_t)src, (lptr_t)dst, 16, 0, 0);
    }
}

// A cluster C: afr slot C&1; reads = base(ks) + const-offset (C*64+fo*16)*64
template<int C>
__device__ __forceinline__ void read_a(s16x8 (&afr)[2][2][2],
                                       const short* bA0, const short* bA1) {
    #pragma unroll
    for (int fo = 0; fo < 2; ++fo)
        #pragma unroll
        for (int ks = 0; ks < 2; ++ks)
            afr[C & 1][fo][ks] =
                *(const s16x8*)((ks ? bA1 : bA0) + (C * 64 + fo * 16) * 64);
}

__device__ __forceinline__ void read_b(s16x8 (&bfr)[4][2],
                                       const short* bB0, const short* bB1) {
    #pragma unroll
    for (int n = 0; n < 4; ++n)
        #pragma unroll
        for (int ks = 0; ks < 2; ++ks)
            bfr[n][ks] = *(const s16x8*)((ks ? bB1 : bB0) + n * 1024);
}

template<int N>
__device__ __forceinline__ void read_b_one(s16x8 (&bfr)[4][2],
                                           const short* bB0, const short* bB1) {
    #pragma unroll
    for (int ks = 0; ks < 2; ++ks)
        bfr[N][ks] = *(const s16x8*)((ks ? bB1 : bB0) + N * 1024);
}

template<int Q>
__device__ __forceinline__ void mfma_quad(f32x4 (&acc)[8][4], s16x8 (&afr)[2][2][2],
                                          s16x8 (&bfr)[4][2]) {
    __builtin_amdgcn_s_setprio(1);
    #pragma unroll
    for (int fo = 0; fo < 2; ++fo)
        #pragma unroll
        for (int n = 0; n < 4; ++n)
            #pragma unroll
            for (int ks = 0; ks < 2; ++ks)
                acc[Q * 2 + fo][n] = __builtin_amdgcn_mfma_f32_16x16x32_bf16(
                    afr[Q & 1][fo][ks], bfr[n][ks], acc[Q * 2 + fo][n], 0, 0, 0);
    __builtin_amdgcn_s_setprio(0);
}

template<int N>
__device__ __forceinline__ void mfma_n3(f32x4 (&acc)[8][4], s16x8 (&afr)[2][2][2],
                                        s16x8 (&bfr)[4][2]) {
    #pragma unroll
    for (int fo = 0; fo < 2; ++fo)
        #pragma unroll
        for (int ks = 0; ks < 2; ++ks)
            acc[6 + fo][N] = __builtin_amdgcn_mfma_f32_16x16x32_bf16(
                afr[1][fo][ks], bfr[N][ks], acc[6 + fo][N], 0, 0, 0);
}

#define MEMCLOB asm volatile("" ::: "memory")
#define BAR     __builtin_amdgcn_s_barrier()
#define SCHED0  __builtin_amdgcn_sched_barrier(0)

#define INTERLEAVE_STEP(N, PP) do {                                           \
    mfma_n3<N>(acc, afr, bfr);                                                \
    read_b_one<N>(bfr, bB0[(PP) ^ 1], bB1[(PP) ^ 1]); } while (0)

// One K-tile, parity P (schedule identical to r6; only addressing changed).
#define TILE_BODY(P) do {                                                     \
    const int t = 2 * t2 + (P);                                               \
    /* p1: issue c1; stage A1(t+1) */                                         \
    read_a<1>(afr, bA0[P], bA1[P]);                                           \
    if (t + 1 < NT) stage<1, 1>(gA, stA[(P) ^ 1]);                            \
    MEMCLOB; BAR;                                                             \
    asm volatile("s_waitcnt lgkmcnt(4)" ::: "memory"); SCHED0;                \
    mfma_quad<0>(acc, afr, bfr);                                              \
    MEMCLOB; BAR;                                                             \
    /* p2: issue c2; stage B0(t+2) */                                         \
    read_a<2>(afr, bA0[P], bA1[P]);                                           \
    if (t + 2 < NT) stage<0, 2>(gB, stB[P]);                                  \
    MEMCLOB; BAR;                                                             \
    asm volatile("s_waitcnt lgkmcnt(4)" ::: "memory"); SCHED0;                \
    mfma_quad<1>(acc, afr, bfr);                                              \
    MEMCLOB; BAR;                                                             \
    /* p3: issue c3; stage B1(t+2) */                                         \
    read_a<3>(afr, bA0[P], bA1[P]);                                           \
    if (t + 2 < NT) stage<1, 2>(gB, stB[P]);                                  \
    MEMCLOB; BAR;                                                             \
    asm volatile("s_waitcnt lgkmcnt(4)" ::: "memory"); SCHED0;                \
    mfma_quad<2>(acc, afr, bfr);                                              \
    MEMCLOB; BAR;                                                             \
    /* p4: counted vmcnt proves t+1 staged; stage A0(t+2); read c0';         */\
    /* drain c3; {mfma-group ; read bfr'} interleave.                        */\
    if (t < NT - 2)       asm volatile("s_waitcnt vmcnt(4)" ::: "memory");    \
    else if (t == NT - 2) asm volatile("s_waitcnt vmcnt(0)" ::: "memory");    \
    MEMCLOB; BAR;                                                             \
    if (t + 2 < NT) stage<0, 2>(gA, stA[P]);                                  \
    if (t + 1 < NT) {                                                         \
        read_a<0>(afr, bA0[(P) ^ 1], bA1[(P) ^ 1]);                           \
        asm volatile("s_waitcnt lgkmcnt(4)" ::: "memory"); SCHED0;            \
        __builtin_amdgcn_s_setprio(1);                                        \
        INTERLEAVE_STEP(0, P); INTERLEAVE_STEP(1, P);                         \
        INTERLEAVE_STEP(2, P); INTERLEAVE_STEP(3, P);                         \
        __builtin_amdgcn_s_setprio(0);                                        \
    } else {                                                                  \
        asm volatile("s_waitcnt lgkmcnt(0)" ::: "memory"); SCHED0;            \
        __builtin_amdgcn_s_setprio(1);                                        \
        mfma_n3<0>(acc, afr, bfr); mfma_n3<1>(acc, afr, bfr);                 \
        mfma_n3<2>(acc, afr, bfr); mfma_n3<3>(acc, afr, bfr);                 \
        __builtin_amdgcn_s_setprio(0);                                        \
    }                                                                         \
    MEMCLOB; BAR;                                                             \
    gA += 64; gB += 64;                                                       \
} while (0)

__global__ __launch_bounds__(512, 2)
void gemm8(const short* __restrict__ A, const short* __restrict__ B,
           float* __restrict__ C) {
    extern __shared__ short smem[];

    const int tid  = threadIdx.x;
    const int lane = tid & 63;
    const int wid  = tid >> 6;
    const int wm   = wid >> 2;      // 0..1
    const int wn   = wid & 3;       // 0..3
    const int r15  = lane & 15;
    const int kg   = lane >> 4;     // 0..3
    const int l8   = lane >> 3;     // 0..7
    const int g16  = (lane & 7) ^ l8;  // pre-swizzled source granule
    const int r7   = r15 & 7;

    const int bid = blockIdx.x;
    const int sw  = (bid & 7) * 64 + (bid >> 3);   // bijective (512 % 8 == 0)
    const int bm  = sw >> 4;   // 0..31
    const int bn  = sw & 15;   // 0..15

    // running per-lane staging sources (advance by 64 shorts per K-tile)
    const short* gA = A + (size_t)(bm * 256 + wid * 16 + l8) * K_TOT + g16 * 8;
    const short* gB = B + (size_t)(bn * 256 + wid * 16 + l8) * K_TOT + g16 * 8;

    // per-parity wave-uniform staging dests (include wid*16 rows)
    short* stA[2] = { smem + wid * 1024, smem + 32768 + wid * 1024 };
    short* stB[2] = { smem + 16384 + wid * 1024, smem + 49152 + wid * 1024 };

    // per-parity ds_read bases: off(row,ks) = row*64 + (((ks<<2|kg)^(row&7))<<3)
    // with row = CONST8 + r15 -> row&7 = r7; granule(ks) lane-const.
    const int gk0 = kg ^ r7;            // ks=0 granule
    const int gk1 = (4 | kg) ^ r7;      // ks=1 granule
    const short* bA0[2], *bA1[2], *bB0[2], *bB1[2];
    #pragma unroll
    for (int p = 0; p < 2; ++p) {
        const short* base = smem + p * 32768;
        bA0[p] = base + (wm * 32 + r15) * 64 + gk0 * 8;
        bA1[p] = base + (wm * 32 + r15) * 64 + gk1 * 8;
        bB0[p] = base + 16384 + (wn * 64 + r15) * 64 + gk0 * 8;
        bB1[p] = base + 16384 + (wn * 64 + r15) * 64 + gk1 * 8;
    }

    // Prologue: tile0 complete + tile1 {B0,B1,A0} = 14 load instrs.
    stage<0, 0>(gB, stB[0]);
    stage<1, 0>(gB, stB[0]);
    stage<0, 0>(gA, stA[0]);
    stage<1, 0>(gA, stA[0]);
    stage<0, 1>(gB, stB[1]);
    stage<1, 1>(gB, stB[1]);
    stage<0, 1>(gA, stA[1]);
    asm volatile("s_waitcnt vmcnt(6)" ::: "memory");  // tile0's 8 loads done
    MEMCLOB; BAR;

    f32x4 acc[8][4];
    #pragma unroll
    for (int f = 0; f < 8; ++f)
        #pragma unroll
        for (int n = 0; n < 4; ++n)
            acc[f][n] = (f32x4){0.f, 0.f, 0.f, 0.f};

    s16x8 afr[2][2][2];
    s16x8 bfr[4][2];

    // Pre-loop: tile0's B + c0 reads in flight (12 ds_reads)
    read_b(bfr, bB0[0], bB1[0]);
    read_a<0>(afr, bA0[0], bA1[0]);

    for (int t2 = 0; t2 < NT / 2; ++t2) {
        TILE_BODY(0);
        TILE_BODY(1);
    }

    // Epilogue: 16x16 C/D layout col=lane&15, row=(lane>>4)*4+jj [m89-verified]
    float* Cp = C + (size_t)(bm * 256 + wm * 32 + kg * 4) * N_TOT
                  + bn * 256 + wn * 64 + r15;
    #pragma unroll
    for (int f = 0; f < 8; ++f)
        #pragma unroll
        for (int n = 0; n < 4; ++n)
            #pragma unroll
            for (int jj = 0; jj < 4; ++jj) {
                const int roff = (f >> 1) * 64 + (f & 1) * 16 + jj;
                Cp[(size_t)roff * N_TOT + n * 16] = acc[f][n][jj];
            }
}

// ---------------- fallback (only if ws too small) ----------------
#define PAD_ROW 40
__global__ __launch_bounds__(256, 2)
void gemm_rs_fused(const float* __restrict__ A, const float* __restrict__ B,
                   float* __restrict__ C) {
    __shared__ short lA[128 * PAD_ROW];
    __shared__ short lB[128 * PAD_ROW];
    const int bid = blockIdx.x;
    const int sw  = (bid & 7) * (int)(gridDim.x >> 3) + (bid >> 3);
    const int bm = sw >> 5, bn = sw & 31;
    const int tid = threadIdx.x, lane = tid & 63, wid = tid >> 6;
    const int wr = wid >> 1, wc = wid & 1, r15 = lane & 15, kg = lane >> 4;
    const int srow = tid >> 1, scg = tid & 1;
    const float* gA = A + ((size_t)(bm * 128 + srow) << 10) + scg * 16;
    const float* gB = B + ((size_t)(bn * 128 + srow) << 10) + scg * 16;
    short* wpA = lA + srow * PAD_ROW + scg * 16;
    short* wpB = lB + srow * PAD_ROW + scg * 16;
    const short* rpA = lA + (wr * 64 + r15) * PAD_ROW + kg * 8;
    const short* rpB = lB + (wc * 64 + r15) * PAD_ROW + kg * 8;
    f32x4 acc[4][4];
    #pragma unroll
    for (int i = 0; i < 4; ++i)
        #pragma unroll
        for (int j = 0; j < 4; ++j) acc[i][j] = (f32x4){0.f, 0.f, 0.f, 0.f};
    for (int t = 0; t < K_TOT / 32; ++t) {
        const int r = t >> 5, k0 = (t & 31) << 5;
        const float* pA = gA + (size_t)r * (M_TOT * LK) + k0;
        const float* pB = gB + (size_t)r * (N_TOT * LK) + k0;
        f32x4 va[4], vb[4];
        #pragma unroll
        for (int q = 0; q < 4; ++q) va[q] = *(const f32x4*)(pA + q * 4);
        #pragma unroll
        for (int q = 0; q < 4; ++q) vb[q] = *(const f32x4*)(pB + q * 4);
        __syncthreads();
        s16x8 oa0, oa1, ob0, ob1;
        #pragma unroll
        for (int q = 0; q < 2; ++q)
            #pragma unroll
            for (int i = 0; i < 4; ++i) {
                oa0[q * 4 + i] = f2bf(va[q][i]);
                oa1[q * 4 + i] = f2bf(va[q + 2][i]);
                ob0[q * 4 + i] = f2bf(vb[q][i]);
                ob1[q * 4 + i] = f2bf(vb[q + 2][i]);
            }
        *(s16x8*)(wpA) = oa0; *(s16x8*)(wpA + 8) = oa1;
        *(s16x8*)(wpB) = ob0; *(s16x8*)(wpB + 8) = ob1;
        __syncthreads();
        s16x8 af[4], bfr2[4];
        #pragma unroll
        for (int i = 0; i < 4; ++i) af[i]   = *(const s16x8*)(rpA + i * 16 * PAD_ROW);
        #pragma unroll
        for (int i = 0; i < 4; ++i) bfr2[i] = *(const s16x8*)(rpB + i * 16 * PAD_ROW);
        #pragma unroll
        for (int i = 0; i < 4; ++i)
            #pragma unroll
            for (int j = 0; j < 4; ++j)
                acc[i][j] = __builtin_amdgcn_mfma_f32_16x16x32_bf16(
                    af[i], bfr2[j], acc[i][j], 0, 0, 0);
    }
    float* Cp = C + (size_t)(bm * 128 + wr * 64 + kg * 4) * N_TOT
                  + bn * 128 + wc * 64 + r15;
    #pragma unroll
    for (int i = 0; i < 4; ++i)
        #pragma unroll
        for (int j = 0; j < 4; ++j)
            #pragma unroll
            for (int jj = 0; jj < 4; ++jj)
                Cp[(size_t)(i * 16 + jj) * N_TOT + j * 16] = acc[i][j][jj];
}

extern "C" void kernel_launch(void* const* d_in, const int* in_sizes, int n_in,
                              void* d_out, int out_size, void* d_ws, size_t ws_size,
                              hipStream_t stream) {
    const float* A = (const float*)d_in[0];   // [8, 8192, 1024]
    const float* B = (const float*)d_in[1];   // [8, 4096, 1024]
    float* C = (float*)d_out;                 // [8192, 4096]

    const size_t needA = (size_t)M_TOT * K_TOT * 2;
    const size_t needB = (size_t)N_TOT * K_TOT * 2;

    if (ws_size >= needA + needB) {
        short* Abf = (short*)d_ws;
        short* Bbf = (short*)((char*)d_ws + needA);
        cvt_all<<<dim3(NR * (M_TOT + N_TOT) / 2), dim3(256), 0, stream>>>(A, B, Abf, Bbf);
        gemm8<<<dim3((M_TOT / 256) * (N_TOT / 256)), dim3(512), 131072, stream>>>(Abf, Bbf, C);
    } else {
        gemm_rs_fused<<<dim3((M_TOT / 128) * (N_TOT / 128)), dim3(256), 0, stream>>>(A, B, C);
    }
}